// Round 2
// baseline (442.314 us; speedup 1.0000x reference)
//
#include <hip/hip_runtime.h>

// Masked dual-branch ConvTranspose2d (stride 2, k3, pad 1, outpad 1), fp32 in/out.
//   out = mask ? (tconv(x, high_w)+hb) : (tconv(xr, low2_w)+lb),  xr = 1x1(x, low1_w)+l1b
// Internally: weights/x-tiles/xr downcast to bf16, mfma_f32_16x16x32_bf16, f32 accum.
// d_ws layout (u16 elems): [0, 4194304) xr (bf16) | [4194304, +36864) whi frags | +10240 wlo frags

typedef unsigned short u16;
typedef unsigned int   u32;
typedef __bf16 bf16x8 __attribute__((ext_vector_type(8)));
typedef u16    u16x8  __attribute__((ext_vector_type(8)));
typedef float  f32x4  __attribute__((ext_vector_type(4)));

#define DEV static __device__ __forceinline__

DEV u16   f2bf(float f){ u32 u = __builtin_bit_cast(u32, f); u += 0x7FFF + ((u >> 16) & 1); return (u16)(u >> 16); }
DEV bf16x8 asb(u16x8 v){ return __builtin_bit_cast(bf16x8, v); }
#define MF(acc, A, B) acc = __builtin_amdgcn_mfma_f32_16x16x32_bf16(asb(A), asb(B), acc, 0, 0, 0)

// ---------------- kernel 0: pre-shuffle weights into MFMA B-fragment order (f32 -> bf16) ----------------
// whi[(tap*2+Q)*4 + tile][lane][e] = bf16(high_w[c=32Q+8*(lane>>4)+e][och=16*tile+(lane&15)][kh][kw])
// wlo[f][tile][lane][e]: packed 2-tap (16ch each) frags; quads 0,1 = tapA, quads 2,3 = tapB.
__global__ __launch_bounds__(256) void wprep(const float* __restrict__ hw, const float* __restrict__ lw,
                                             u16* __restrict__ whi, u16* __restrict__ wlo)
{
  int t = blockIdx.x * 256 + threadIdx.x;
  if (t < 36864) {
    int e = t & 7, lane = (t >> 3) & 63, tile = (t >> 9) & 3, Q = (t >> 11) & 1, tap = t >> 12;
    int q = lane >> 4, n = lane & 15;
    int c = 32 * Q + 8 * q + e, och = 16 * tile + n;
    whi[t] = f2bf(hw[(c * 64 + och) * 9 + tap]);
  } else if (t < 47104) {
    int t2 = t - 36864;
    int e = t2 & 7, lane = (t2 >> 3) & 63, tile = (t2 >> 9) & 3, f = t2 >> 11;
    int q = lane >> 4, n = lane & 15, och = 16 * tile + n;
    // f: {P00:(1,1)|zero, P01:(1,0)|(1,2), P10:(0,1)|(2,1), P11a:(0,0)|(0,2), P11b:(2,0)|(2,2)}
    const int ta[10] = {4, -1, 3, 5, 1, 7, 0, 2, 6, 8};
    int tap = ta[f * 2 + (q >> 1)];
    u16 v = 0;
    if (tap >= 0) { int c = 8 * (q & 1) + e; v = f2bf(lw[(c * 64 + och) * 9 + tap]); }
    wlo[t2] = v;
  }
}

// ---------------- kernel 1: xr[b][i][j][16] = bf16(low1_w (16x64) @ x + l1b) ----------------
__global__ __launch_bounds__(256) void xr_kernel(const float* __restrict__ x, const float* __restrict__ w1,
                                                 const float* __restrict__ b1, u16* __restrict__ xr)
{
  __shared__ float sw[1024];  // [c][r]
  __shared__ float sb[16];
  for (int u = threadIdx.x; u < 1024; u += 256) { int r = u & 15, c = u >> 4; sw[u] = w1[r * 64 + c]; }
  if (threadIdx.x < 16) sb[threadIdx.x] = b1[threadIdx.x];
  __syncthreads();
  int t = blockIdx.x * 256 + threadIdx.x;        // = (b*256 + i)*256 + j
  const float* xp = x + ((size_t)(t >> 16) << 22) + (t & 65535);
  float acc[16];
  #pragma unroll
  for (int r = 0; r < 16; ++r) acc[r] = sb[r];
  #pragma unroll 4
  for (int c = 0; c < 64; ++c) {
    float xv = xp[(size_t)c << 16];
    #pragma unroll
    for (int r = 0; r < 16; ++r) acc[r] = fmaf(xv, sw[c * 16 + r], acc[r]);
  }
  u32 pk[8];
  #pragma unroll
  for (int k = 0; k < 8; ++k) pk[k] = (u32)f2bf(acc[2 * k]) | ((u32)f2bf(acc[2 * k + 1]) << 16);
  uint4* dst = (uint4*)(xr + (size_t)t * 16);
  dst[0] = make_uint4(pk[0], pk[1], pk[2], pk[3]);
  dst[1] = make_uint4(pk[4], pk[5], pk[6], pk[7]);
}

// ---------------- kernel 2: 4-phase tconv + blend ----------------
// Block: (jchunk, i, b). Output rows 2i,2i+1, cols 2*j0..2*j0+127, all 64 och.
// Wave w -> och tile 16w. M=16 pixels (lane&15), N=16 och, K=channels.
__global__ __launch_bounds__(256) void tconv_main(
    const float* __restrict__ x, const u16* __restrict__ xr,
    const u16* __restrict__ whi, const u16* __restrict__ wlo,
    const float* __restrict__ mask, const float* __restrict__ hbp,
    const float* __restrict__ lbp, float* __restrict__ out)
{
  __shared__ __attribute__((aligned(16))) u16 xs [2][68][72];  // [row][col][ch64 pad72] 144B col stride
  __shared__ __attribute__((aligned(16))) u16 xrs[2][68][24];  // [row][col][ch16 pad24]; ch16..23 zeroed

  const int tid  = threadIdx.x;
  const int lane = tid & 63, wid = tid >> 6;
  const int j0 = blockIdx.x * 64;
  const int i  = blockIdx.y;
  const int b  = blockIdx.z;
  const int q  = lane >> 4, n = lane & 15;

  // B-fragments in registers (coalesced 16B/lane from pre-shuffled layout)
  u16x8 bh[9][2], bl[5];
  {
    const u16x8* wh8 = (const u16x8*)whi;
    #pragma unroll
    for (int tap = 0; tap < 9; ++tap)
      #pragma unroll
      for (int Q = 0; Q < 2; ++Q)
        bh[tap][Q] = wh8[((tap * 2 + Q) * 4 + wid) * 64 + lane];
    const u16x8* wl8 = (const u16x8*)wlo;
    #pragma unroll
    for (int f = 0; f < 5; ++f) bl[f] = wl8[(f * 4 + wid) * 64 + lane];
  }
  const int och = 16 * wid + n;
  const float hbias = hbp[och];
  const float lbias = lbp[och];

  // stage x rows {i,i+1}, cols j0..j0+63 (float2), downcast bf16, transpose to ch-contiguous
  for (int idx = tid; idx < 2 * 64 * 32; idx += 256) {
    int cp = idx & 31, c = (idx >> 5) & 63, row = idx >> 11;
    int gi = i + row, col = cp * 2;
    float2 v = make_float2(0.f, 0.f);
    if (gi < 256) v = *(const float2*)&x[((size_t)b << 22) + ((size_t)c << 16) + (gi << 8) + (j0 + col)];
    xs[row][col    ][c] = f2bf(v.x);
    xs[row][col + 1][c] = f2bf(v.y);
  }
  if (tid < 128) {  // halo col 64
    int row = tid >> 6, c = tid & 63, gi = i + row, gj = j0 + 64;
    float v = 0.f;
    if (gi < 256 && gj < 256) v = x[((size_t)b << 22) + ((size_t)c << 16) + (gi << 8) + gj];
    xs[row][64][c] = f2bf(v);
  }
  // stage xr (bf16 in ws) rows {i,i+1}, cols j0..j0+64 (contiguous dwords in global)
  for (int u = tid; u < 1040; u += 256) {
    int row = (u >= 520) ? 1 : 0;
    int uu  = u - row * 520;
    int col = uu >> 3, rcp = uu & 7;
    int gi = i + row, gj = j0 + col;
    u32 v = 0;
    if (gi < 256 && gj < 256) v = *(const u32*)(xr + ((size_t)((b * 256 + gi) * 256 + gj)) * 16 + rcp * 2);
    *(u32*)&xrs[row][col][rcp * 2] = v;
  }
  if (tid < 136) {  // zero pad channels (used as the zero half of the P00 low frag)
    int row = tid / 68, col = tid % 68;
    *(uint4*)&xrs[row][col][16] = make_uint4(0, 0, 0, 0);
  }
  __syncthreads();

  #pragma unroll
  for (int jt = 0; jt < 64; jt += 16) {
    const int colb = jt + n;   // A-frag: pixel m = lane&15
    u16x8 ah[2][2][2];         // [row][dx][Q]
    #pragma unroll
    for (int r = 0; r < 2; ++r)
      #pragma unroll
      for (int d = 0; d < 2; ++d)
        #pragma unroll
        for (int Q = 0; Q < 2; ++Q)
          ah[r][d][Q] = *(const u16x8*)&xs[r][colb + d][32 * Q + 8 * q];
    const int dq = (q < 2) ? 1 : 0;  // quads 0,1 = tapA / quads 2,3 = tapB
    u16x8 lf0 = *(const u16x8*)&xrs[0 ][colb     ][(q < 2) ? 8 * (q & 1) : 16];
    u16x8 lf1 = *(const u16x8*)&xrs[0 ][colb + dq][8 * (q & 1)];
    u16x8 lf2 = *(const u16x8*)&xrs[dq][colb     ][8 * (q & 1)];
    u16x8 lf3 = *(const u16x8*)&xrs[1 ][colb + dq][8 * (q & 1)];

    auto epi = [&](f32x4 hi, f32x4 lo, int py, int px) {
      int y = 2 * i + py;
      #pragma unroll
      for (int reg = 0; reg < 4; ++reg) {       // D: row(pixel) = 4q+reg, col(och) = lane&15
        int pix = jt + 4 * q + reg;
        int xc  = 2 * (j0 + pix) + px;
        float mk = mask[((b * 512 + y) << 9) + xc];
        float hv = hi[reg] + hbias;
        float lv = lo[reg] + lbias;
        out[((size_t)(b * 64 + och) << 18) + ((size_t)y << 9) + xc] = lv + mk * (hv - lv);
      }
    };

    const f32x4 z4 = {0.f, 0.f, 0.f, 0.f};
    f32x4 hi, lo;
    // phase (0,0): w(1,1)@(i,j)
    hi = z4; lo = z4;
    MF(hi, ah[0][0][0], bh[4][0]); MF(hi, ah[0][0][1], bh[4][1]);
    MF(lo, lf0, bl[0]);
    epi(hi, lo, 0, 0);
    // phase (0,1): w(1,0)@(i,j+1) + w(1,2)@(i,j)
    hi = z4; lo = z4;
    MF(hi, ah[0][1][0], bh[3][0]); MF(hi, ah[0][1][1], bh[3][1]);
    MF(hi, ah[0][0][0], bh[5][0]); MF(hi, ah[0][0][1], bh[5][1]);
    MF(lo, lf1, bl[1]);
    epi(hi, lo, 0, 1);
    // phase (1,0): w(0,1)@(i+1,j) + w(2,1)@(i,j)
    hi = z4; lo = z4;
    MF(hi, ah[1][0][0], bh[1][0]); MF(hi, ah[1][0][1], bh[1][1]);
    MF(hi, ah[0][0][0], bh[7][0]); MF(hi, ah[0][0][1], bh[7][1]);
    MF(lo, lf2, bl[2]);
    epi(hi, lo, 1, 0);
    // phase (1,1): w(0,0)@(i+1,j+1) + w(0,2)@(i+1,j) + w(2,0)@(i,j+1) + w(2,2)@(i,j)
    hi = z4; lo = z4;
    MF(hi, ah[1][1][0], bh[0][0]); MF(hi, ah[1][1][1], bh[0][1]);
    MF(hi, ah[1][0][0], bh[2][0]); MF(hi, ah[1][0][1], bh[2][1]);
    MF(hi, ah[0][1][0], bh[6][0]); MF(hi, ah[0][1][1], bh[6][1]);
    MF(hi, ah[0][0][0], bh[8][0]); MF(hi, ah[0][0][1], bh[8][1]);
    MF(lo, lf3, bl[3]); MF(lo, lf1, bl[4]);
    epi(hi, lo, 1, 1);
  }
}

extern "C" void kernel_launch(void* const* d_in, const int* in_sizes, int n_in,
                              void* d_out, int out_size, void* d_ws, size_t ws_size,
                              hipStream_t stream)
{
  const float* x    = (const float*)d_in[0];
  const float* mask = (const float*)d_in[1];
  // d_in[2] = inv_mask, unused (mask is exactly 0.0/1.0)
  const float* hw   = (const float*)d_in[3];
  const float* hb   = (const float*)d_in[4];
  const float* l1w  = (const float*)d_in[5];
  const float* l1b  = (const float*)d_in[6];
  const float* l2w  = (const float*)d_in[7];
  const float* l2b  = (const float*)d_in[8];
  float* out = (float*)d_out;
  u16* ws  = (u16*)d_ws;
  u16* xr  = ws;                 // 4*256*256*16 = 4194304 elems (bf16)
  u16* whi = ws + 4194304;       // 36864 elems
  u16* wlo = whi + 36864;        // 10240 elems

  wprep<<<184, 256, 0, stream>>>(hw, l2w, whi, wlo);
  xr_kernel<<<1024, 256, 0, stream>>>(x, l1w, l1b, xr);
  tconv_main<<<dim3(4, 256, 4), 256, 0, stream>>>(x, xr, whi, wlo, mask, hb, l2b, out);
}